// Round 2
// baseline (168.091 us; speedup 1.0000x reference)
//
#include <hip/hip_runtime.h>

using u16 = unsigned short;
using u32 = unsigned int;
using u64 = unsigned long long;

// ---------- bf16 helpers ----------
__device__ __forceinline__ float bf2f(u32 bits16) {
    return __uint_as_float(bits16 << 16);
}
// round-to-nearest-even f32 -> bf16 bits
__device__ __forceinline__ u32 f2bf(float f) {
    u32 u = __float_as_uint(f);
    return (u + 0x7FFFu + ((u >> 16) & 1u)) >> 16;
}

#define WF_FLAG 1160   // float-slot index in d_ws where dtype flag lives

// ---------- dtype detector: is x bf16 (flag=1) or f32 (flag=0)? ----------
// If x is bf16, every dword is two [0,1) bf16s: low u16 has sign=0, exp<=0x7E.
// If x is f32, low u16 is random mantissa bits: fails that test ~75% of the time.
__global__ void detect_kernel(const u32* __restrict__ x, u32* __restrict__ flag) {
    int lane = threadIdx.x;              // launched with 64 threads
    u32 d  = x[lane * 997];              // max idx 62811 dwords < 8.4M (bf16 size)
    u32 lo = d & 0xFFFFu;
    u32 ex = (lo >> 7) & 0xFFu;
    bool plausible = ((lo & 0x8000u) == 0) && (ex <= 0x7Eu);
    u64 m = __ballot(plausible);
    if (lane == 0) flag[0] = (__popcll(m) >= 56) ? 1u : 0u;
}

// ---------- weight conversion: (bf16|f32) -> f32 into d_ws ----------
// layout (floats): qw@0[8] W1@8[64] b1@72[16] W2@88[512] b2@600[32] W3@632[512] b3@1144[16]
__device__ __forceinline__ float rdw(const void* p, int i, bool bf) {
    return bf ? bf2f(((const u16*)p)[i]) : ((const float*)p)[i];
}

__global__ void cvt_weights_kernel(
    const void* qw, const void* W1, const void* b1,
    const void* W2, const void* b2, const void* W3, const void* b3,
    float* __restrict__ o)
{
    bool bf = (reinterpret_cast<const u32*>(o)[WF_FLAG] != 0);
    int t = blockIdx.x * blockDim.x + threadIdx.x;
    if (t >= 1160) return;
    float v;
    if      (t <    8) v = rdw(qw, t,        bf);
    else if (t <   72) v = rdw(W1, t - 8,    bf);
    else if (t <   88) v = rdw(b1, t - 72,   bf);
    else if (t <  600) v = rdw(W2, t - 88,   bf);
    else if (t <  632) v = rdw(b2, t - 600,  bf);
    else if (t < 1144) v = rdw(W3, t - 632,  bf);
    else               v = rdw(b3, t - 1144, bf);
    o[t] = v;
}

// ---------- main fused kernel ----------
// One thread per batch element; 16 complex amps in registers.
// DIRECT=true is the no-workspace fallback (assumes f32 weights from d_in).
template<bool DIRECT>
__global__ void __launch_bounds__(256) qae_main(
    const void* __restrict__ xv,
    const float* __restrict__ wf,
    const void* qwp, const void* W1p, const void* W2p, const void* W3p,
    const void* b1p, const void* b2p, const void* b3p,
    void* __restrict__ outv, int n)
{
    int b = blockIdx.x * blockDim.x + threadIdx.x;
    if (b >= n) return;

    bool bf = DIRECT ? false
                     : (reinterpret_cast<const u32*>(wf)[WF_FLAG] != 0);

    // uniform weight getters (scalar loads from converted f32 table)
    auto GQ  = [&](int i) { return DIRECT ? ((const float*)qwp)[i] : wf[i]; };
    auto GW1 = [&](int i) { return DIRECT ? ((const float*)W1p)[i] : wf[8 + i]; };
    auto GB1 = [&](int i) { return DIRECT ? ((const float*)b1p)[i] : wf[72 + i]; };
    auto GW2 = [&](int i) { return DIRECT ? ((const float*)W2p)[i] : wf[88 + i]; };
    auto GB2 = [&](int i) { return DIRECT ? ((const float*)b2p)[i] : wf[600 + i]; };
    auto GW3 = [&](int i) { return DIRECT ? ((const float*)W3p)[i] : wf[632 + i]; };
    auto GB3 = [&](int i) { return DIRECT ? ((const float*)b3p)[i] : wf[1144 + i]; };

    // ---- load the 8 used features (x[:,0..7]) in the detected dtype ----
    float th[4], ph[4];
    if (bf) {
        uint4 xw = reinterpret_cast<const uint4*>(xv)[(size_t)b * 2];  // 16B of 32B row
        th[0] = bf2f(xw.x & 0xFFFFu); th[1] = bf2f(xw.x >> 16);
        th[2] = bf2f(xw.y & 0xFFFFu); th[3] = bf2f(xw.y >> 16);
        ph[0] = bf2f(xw.z & 0xFFFFu); ph[1] = bf2f(xw.z >> 16);
        ph[2] = bf2f(xw.w & 0xFFFFu); ph[3] = bf2f(xw.w >> 16);
    } else {
        const float4* xf = reinterpret_cast<const float4*>(xv);        // 32B of 64B row
        float4 a = xf[(size_t)b * 4];
        float4 c = xf[(size_t)b * 4 + 1];
        th[0] = a.x; th[1] = a.y; th[2] = a.z; th[3] = a.w;
        ph[0] = c.x; ph[1] = c.y; ph[2] = c.z; ph[3] = c.w;
    }

    // ---- layer 1 on |0>: per-qubit u = RZ(phi)RY(theta)|0>
    //  u0 = cos(th/2) e^{-i phi/2},  u1 = sin(th/2) e^{+i phi/2}
    //  angle = x*pi, half-angle = x*pi/2 -> v_sin revolutions = x/4
    float u0r[4], u0i[4], u1r[4], u1i[4];
    #pragma unroll
    for (int i = 0; i < 4; ++i) {
        float ct = __builtin_amdgcn_cosf(th[i] * 0.25f);
        float st = __builtin_amdgcn_sinf(th[i] * 0.25f);
        float cp = __builtin_amdgcn_cosf(ph[i] * 0.25f);
        float sp = __builtin_amdgcn_sinf(ph[i] * 0.25f);
        u0r[i] = ct * cp;  u0i[i] = -ct * sp;
        u1r[i] = st * cp;  u1i[i] = st * sp;
    }

    // ---- tensor product -> 16 amps, idx = q0*8 + q1*4 + q2*2 + q3 ----
    float p01r[4], p01i[4], p23r[4], p23i[4];
    #pragma unroll
    for (int a = 0; a < 2; ++a) {
        #pragma unroll
        for (int c = 0; c < 2; ++c) {
            float arq = a ? u1r[0] : u0r[0], aiq = a ? u1i[0] : u0i[0];
            float brq = c ? u1r[1] : u0r[1], biq = c ? u1i[1] : u0i[1];
            p01r[a*2+c] = arq*brq - aiq*biq;
            p01i[a*2+c] = arq*biq + aiq*brq;
            float crq = a ? u1r[2] : u0r[2], ciq = a ? u1i[2] : u0i[2];
            float drq = c ? u1r[3] : u0r[3], diq = c ? u1i[3] : u0i[3];
            p23r[a*2+c] = crq*drq - ciq*diq;
            p23i[a*2+c] = crq*diq + ciq*drq;
        }
    }
    float sr[16], si[16];
    #pragma unroll
    for (int hi = 0; hi < 4; ++hi)
        #pragma unroll
        for (int lo = 0; lo < 4; ++lo) {
            sr[hi*4+lo] = p01r[hi]*p23r[lo] - p01i[hi]*p23i[lo];
            si[hi*4+lo] = p01r[hi]*p23i[lo] + p01i[hi]*p23r[lo];
        }

    // ---- CNOT chain (0,1),(1,2),(2,3): new[i]=old[g(i)],
    //      g(q0,q1,q2,q3) = (q0, q1^q0, q2^q1, q3^q2)  [register renames] ----
    float tr[16], ti[16];
    #pragma unroll
    for (int i = 0; i < 16; ++i) {
        int q0 = (i>>3)&1, q1 = (i>>2)&1, q2 = (i>>1)&1, q3 = i&1;
        int g = (q0<<3) | ((q1^q0)<<2) | ((q2^q1)<<1) | (q3^q2);
        tr[i] = sr[g]; ti[i] = si[g];
    }

    // ---- trainable layer: RY(qw[2w]) then RZ(qw[2w+1]) on qubit w ----
    const float INV4PI = 0.07957747154594767f;   // half-angle -> revolutions
    #pragma unroll
    for (int w = 0; w < 4; ++w) {
        float al = GQ(2*w), be = GQ(2*w+1);
        float c  = __builtin_amdgcn_cosf(al * INV4PI);
        float s  = __builtin_amdgcn_sinf(al * INV4PI);
        float pc = __builtin_amdgcn_cosf(be * INV4PI);
        float ps = __builtin_amdgcn_sinf(be * INV4PI);
        int stride = 1 << (3 - w);   // qubit w is bit (3-w)
        #pragma unroll
        for (int m = 0; m < 16; ++m) {
            if (m & stride) continue;
            int i0 = m, i1 = m | stride;
            float n0r = c*tr[i0] - s*tr[i1];
            float n0i = c*ti[i0] - s*ti[i1];
            float n1r = s*tr[i0] + c*tr[i1];
            float n1i = s*ti[i0] + c*ti[i1];
            tr[i0] = n0r*pc + n0i*ps;          // * e^{-i be/2}
            ti[i0] = n0i*pc - n0r*ps;
            tr[i1] = n1r*pc - n1i*ps;          // * e^{+i be/2}
            ti[i1] = n1i*pc + n1r*ps;
        }
    }

    // ---- second CNOT chain (same permutation) ----
    float fr[16], fi[16];
    #pragma unroll
    for (int i = 0; i < 16; ++i) {
        int q0 = (i>>3)&1, q1 = (i>>2)&1, q2 = (i>>1)&1, q3 = i&1;
        int g = (q0<<3) | ((q1^q0)<<2) | ((q2^q1)<<1) | (q3^q2);
        fr[i] = tr[g]; fi[i] = ti[g];
    }

    // ---- PauliZ expectations via partial-sum tree ----
    float p[16];
    #pragma unroll
    for (int i = 0; i < 16; ++i) p[i] = fr[i]*fr[i] + fi[i]*fi[i];
    float s2[8], s4[4];
    #pragma unroll
    for (int j = 0; j < 8; ++j) s2[j] = p[2*j] + p[2*j+1];
    #pragma unroll
    for (int j = 0; j < 4; ++j) s4[j] = s2[2*j] + s2[2*j+1];
    float z0 = (s4[0] + s4[1]) - (s4[2] + s4[3]);
    float z1 = (s4[0] - s4[1]) + (s4[2] - s4[3]);
    float z2 = (s2[0] - s2[1]) + (s2[2] - s2[3]) + (s2[4] - s2[5]) + (s2[6] - s2[7]);
    float z3 = (p[0]-p[1]) + (p[2]-p[3]) + (p[4]-p[5]) + (p[6]-p[7])
             + (p[8]-p[9]) + (p[10]-p[11]) + (p[12]-p[13]) + (p[14]-p[15]);
    float zv[4] = { z0, z1, z2, z3 };

    // ---- decoder MLP: 4 -> 16 -> relu -> 32 -> relu -> 16 ----
    float h1[16];
    #pragma unroll
    for (int j = 0; j < 16; ++j) {
        float acc = GB1(j);
        #pragma unroll
        for (int k = 0; k < 4; ++k) acc = fmaf(GW1(j*4+k), zv[k], acc);
        h1[j] = fmaxf(acc, 0.f);
    }
    float h2[32];
    #pragma unroll
    for (int j = 0; j < 32; ++j) {
        float acc = GB2(j);
        #pragma unroll
        for (int k = 0; k < 16; ++k) acc = fmaf(GW2(j*16+k), h1[k], acc);
        h2[j] = fmaxf(acc, 0.f);
    }
    float o[16];
    #pragma unroll
    for (int j = 0; j < 16; ++j) {
        float acc = GB3(j);
        #pragma unroll
        for (int k = 0; k < 32; ++k) acc = fmaf(GW3(j*32+k), h2[k], acc);
        o[j] = acc;
    }

    // ---- store in the detected dtype ----
    if (bf) {
        u32 ow[8];
        #pragma unroll
        for (int j = 0; j < 8; ++j) ow[j] = f2bf(o[2*j]) | (f2bf(o[2*j+1]) << 16);
        uint4* op = reinterpret_cast<uint4*>(outv) + (size_t)b * 2;
        op[0] = make_uint4(ow[0], ow[1], ow[2], ow[3]);
        op[1] = make_uint4(ow[4], ow[5], ow[6], ow[7]);
    } else {
        float4* op = reinterpret_cast<float4*>(outv) + (size_t)b * 4;
        op[0] = make_float4(o[0],  o[1],  o[2],  o[3]);
        op[1] = make_float4(o[4],  o[5],  o[6],  o[7]);
        op[2] = make_float4(o[8],  o[9],  o[10], o[11]);
        op[3] = make_float4(o[12], o[13], o[14], o[15]);
    }
}

extern "C" void kernel_launch(void* const* d_in, const int* in_sizes, int n_in,
                              void* d_out, int out_size, void* d_ws, size_t ws_size,
                              hipStream_t stream) {
    const void* x  = d_in[0];
    const void* qw = d_in[1];
    const void* W1 = d_in[2];
    const void* b1 = d_in[3];
    const void* W2 = d_in[4];
    const void* b2 = d_in[5];
    const void* W3 = d_in[6];
    const void* b3 = d_in[7];

    int n = in_sizes[0] / 16;           // B
    int blocks = (n + 255) / 256;

    if (ws_size >= (WF_FLAG + 1) * sizeof(float)) {
        float* wf = (float*)d_ws;
        detect_kernel<<<1, 64, 0, stream>>>((const u32*)x, (u32*)wf + WF_FLAG);
        cvt_weights_kernel<<<5, 256, 0, stream>>>(qw, W1, b1, W2, b2, W3, b3, wf);
        qae_main<false><<<blocks, 256, 0, stream>>>(x, wf, qw, W1, W2, W3,
                                                    b1, b2, b3, d_out, n);
    } else {
        // no workspace: assume reference dtype (f32) and read weights directly
        qae_main<true><<<blocks, 256, 0, stream>>>(x, nullptr, qw, W1, W2, W3,
                                                   b1, b2, b3, d_out, n);
    }
}

// Round 3
// 149.333 us; speedup vs baseline: 1.1256x; 1.1256x over previous
//
#include <hip/hip_runtime.h>
#include <math.h>

using u32 = unsigned int;
typedef float v2f __attribute__((ext_vector_type(2)));

__device__ __forceinline__ v2f pkfma(v2f a, v2f b, v2f c) {
    return __builtin_elementwise_fma(a, b, c);   // -> v_pk_fma_f32
}
__device__ __forceinline__ v2f s2(float x) { return (v2f){x, x}; }

// ---------- workspace layout (floats) ----------
// T1@0[64]   : T1[k*16+j] = W1[j*4+k]      (k<4,  j<16)
// B1@64[16]
// T2@80[512] : T2[k*32+j] = W2[j*16+k]     (k<16, j<32)
// B2@592[32]
// T3@624[512]: T3[k*16+j] = W3[j*32+k]     (k<32, j<16)
// B3@1136[16]
// QC@1152[4] : cos(qw[2w]/2)   QS@1156[4] : sin(qw[2w]/2)
#define WS_FLOATS 1160

__global__ void cvt_weights_kernel(
    const float* __restrict__ qw, const float* __restrict__ W1, const float* __restrict__ b1,
    const float* __restrict__ W2, const float* __restrict__ b2, const float* __restrict__ W3,
    const float* __restrict__ b3, float* __restrict__ o)
{
    int t = blockIdx.x * blockDim.x + threadIdx.x;
    if (t >= WS_FLOATS) return;
    float v;
    if (t < 64) {                      // T1
        int k = t >> 4, j = t & 15;
        v = W1[j * 4 + k];
    } else if (t < 80) {               // B1
        v = b1[t - 64];
    } else if (t < 592) {              // T2
        int idx = t - 80, k = idx >> 5, j = idx & 31;
        v = W2[j * 16 + k];
    } else if (t < 624) {              // B2
        v = b2[t - 592];
    } else if (t < 1136) {             // T3
        int idx = t - 624, k = idx >> 4, j = idx & 15;
        v = W3[j * 32 + k];
    } else if (t < 1152) {             // B3
        v = b3[t - 1136];
    } else if (t < 1156) {             // QC
        v = cosf(qw[2 * (t - 1152)] * 0.5f);
    } else {                           // QS
        v = sinf(qw[2 * (t - 1156)] * 0.5f);
    }
    o[t] = v;
}

// ---------- main fused kernel (f32 in / f32 out) ----------
// One thread per batch element; 16 complex amps in registers as (r,i) v2f.
// Trainable RZ layer dropped: diagonal phases are invisible to |amp|^2
// after a basis permutation (CNOT chain) — mathematically exact.
template<bool WS>
__global__ void __launch_bounds__(256) qae_main(
    const float* __restrict__ x,
    const float* __restrict__ wf,
    const float* __restrict__ qwp,
    const float* __restrict__ W1p, const float* __restrict__ b1p,
    const float* __restrict__ W2p, const float* __restrict__ b2p,
    const float* __restrict__ W3p, const float* __restrict__ b3p,
    float* __restrict__ outv, int n)
{
    int b = blockIdx.x * blockDim.x + threadIdx.x;
    if (b >= n) return;

    // uniform weight accessors (s_load; WS path reads pre-transposed pairs)
    auto T1v = [&](int k, int j) -> v2f {   // {W1[2j][k], W1[2j+1][k]}
        if (WS) { int o = k * 16 + 2 * j; return (v2f){wf[o], wf[o + 1]}; }
        return (v2f){W1p[(2 * j) * 4 + k], W1p[(2 * j + 1) * 4 + k]};
    };
    auto T2v = [&](int k, int j) -> v2f {
        if (WS) { int o = 80 + k * 32 + 2 * j; return (v2f){wf[o], wf[o + 1]}; }
        return (v2f){W2p[(2 * j) * 16 + k], W2p[(2 * j + 1) * 16 + k]};
    };
    auto T3v = [&](int k, int j) -> v2f {
        if (WS) { int o = 624 + k * 16 + 2 * j; return (v2f){wf[o], wf[o + 1]}; }
        return (v2f){W3p[(2 * j) * 32 + k], W3p[(2 * j + 1) * 32 + k]};
    };
    auto B1v = [&](int j) -> v2f {
        if (WS) return (v2f){wf[64 + 2 * j], wf[64 + 2 * j + 1]};
        return (v2f){b1p[2 * j], b1p[2 * j + 1]};
    };
    auto B2v = [&](int j) -> v2f {
        if (WS) return (v2f){wf[592 + 2 * j], wf[592 + 2 * j + 1]};
        return (v2f){b2p[2 * j], b2p[2 * j + 1]};
    };
    auto B3v = [&](int j) -> v2f {
        if (WS) return (v2f){wf[1136 + 2 * j], wf[1136 + 2 * j + 1]};
        return (v2f){b3p[2 * j], b3p[2 * j + 1]};
    };

    // ---- load the 8 used features: first 32B of the 64B row ----
    const float4* xf = reinterpret_cast<const float4*>(x);
    float4 xa = xf[(size_t)b * 4];
    float4 xc = xf[(size_t)b * 4 + 1];
    float th[4] = { xa.x, xa.y, xa.z, xa.w };
    float ph[4] = { xc.x, xc.y, xc.z, xc.w };

    // ---- layer 1 on |0>: per-qubit u = RZ(phi)RY(theta)|0>
    //  u0 = cos(th/2) e^{-i phi/2},  u1 = sin(th/2) e^{+i phi/2}
    //  angle = x*pi, half-angle = x*pi/2 -> v_sin revolutions = x/4
    float u0r[4], u0i[4], u1r[4], u1i[4];
    #pragma unroll
    for (int i = 0; i < 4; ++i) {
        float ct = __builtin_amdgcn_cosf(th[i] * 0.25f);
        float st = __builtin_amdgcn_sinf(th[i] * 0.25f);
        float cp = __builtin_amdgcn_cosf(ph[i] * 0.25f);
        float sp = __builtin_amdgcn_sinf(ph[i] * 0.25f);
        u0r[i] = ct * cp;  u0i[i] = -ct * sp;
        u1r[i] = st * cp;  u1i[i] = st * sp;
    }

    // ---- tensor product -> 16 amps, idx = q0*8 + q1*4 + q2*2 + q3 ----
    float p01r[4], p01i[4], p23r[4], p23i[4];
    #pragma unroll
    for (int a = 0; a < 2; ++a) {
        #pragma unroll
        for (int c = 0; c < 2; ++c) {
            float arq = a ? u1r[0] : u0r[0], aiq = a ? u1i[0] : u0i[0];
            float brq = c ? u1r[1] : u0r[1], biq = c ? u1i[1] : u0i[1];
            p01r[a*2+c] = arq*brq - aiq*biq;
            p01i[a*2+c] = arq*biq + aiq*brq;
            float crq = a ? u1r[2] : u0r[2], ciq = a ? u1i[2] : u0i[2];
            float drq = c ? u1r[3] : u0r[3], diq = c ? u1i[3] : u0i[3];
            p23r[a*2+c] = crq*drq - ciq*diq;
            p23i[a*2+c] = crq*diq + ciq*drq;
        }
    }

    // amps as v2f (r,i), with first CNOT chain folded in as an index rename:
    // new[i] = old[g(i)], g(q0,q1,q2,q3) = (q0, q1^q0, q2^q1, q3^q2)
    v2f amp[16];
    #pragma unroll
    for (int i = 0; i < 16; ++i) {
        int q0 = (i>>3)&1, q1 = (i>>2)&1, q2 = (i>>1)&1, q3 = i&1;
        int g = (q0<<3) | ((q1^q0)<<2) | ((q2^q1)<<1) | (q3^q2);
        int hi = g >> 2, lo = g & 3;
        amp[i] = (v2f){ p01r[hi]*p23r[lo] - p01i[hi]*p23i[lo],
                        p01r[hi]*p23i[lo] + p01i[hi]*p23r[lo] };
    }

    // ---- trainable RY layer (RZ dropped — phase-invisible) ----
    #pragma unroll
    for (int w = 0; w < 4; ++w) {
        float c, s;
        if (WS) { c = wf[1152 + w]; s = wf[1156 + w]; }
        else {
            const float INV4PI = 0.07957747154594767f;   // half-angle -> revolutions
            c = __builtin_amdgcn_cosf(qwp[2*w] * INV4PI);
            s = __builtin_amdgcn_sinf(qwp[2*w] * INV4PI);
        }
        v2f vc = s2(c), vs = s2(s);
        int stride = 1 << (3 - w);   // qubit w is bit (3-w)
        #pragma unroll
        for (int m = 0; m < 16; ++m) {
            if (m & stride) continue;
            int i0 = m, i1 = m | stride;
            v2f a0 = amp[i0], a1 = amp[i1];
            amp[i0] = pkfma(vc, a0, -(vs * a1));
            amp[i1] = pkfma(vc, a1,  (vs * a0));
        }
    }

    // ---- second CNOT chain (rename) + probabilities ----
    float p[16];
    #pragma unroll
    for (int i = 0; i < 16; ++i) {
        int q0 = (i>>3)&1, q1 = (i>>2)&1, q2 = (i>>1)&1, q3 = i&1;
        int g = (q0<<3) | ((q1^q0)<<2) | ((q2^q1)<<1) | (q3^q2);
        v2f q = amp[g] * amp[g];
        p[i] = q.x + q.y;
    }

    // ---- PauliZ expectations via partial-sum tree ----
    float s2a[8], s4[4];
    #pragma unroll
    for (int j = 0; j < 8; ++j) s2a[j] = p[2*j] + p[2*j+1];
    #pragma unroll
    for (int j = 0; j < 4; ++j) s4[j] = s2a[2*j] + s2a[2*j+1];
    float z0 = (s4[0] + s4[1]) - (s4[2] + s4[3]);
    float z1 = (s4[0] - s4[1]) + (s4[2] - s4[3]);
    float z2 = (s2a[0] - s2a[1]) + (s2a[2] - s2a[3]) + (s2a[4] - s2a[5]) + (s2a[6] - s2a[7]);
    float z3 = (p[0]-p[1]) + (p[2]-p[3]) + (p[4]-p[5]) + (p[6]-p[7])
             + (p[8]-p[9]) + (p[10]-p[11]) + (p[12]-p[13]) + (p[14]-p[15]);
    float zv[4] = { z0, z1, z2, z3 };

    // ---- decoder MLP with packed f32: 4 -> 16 -> relu -> 32 -> relu -> 16 ----
    const v2f vzero = s2(0.f);

    v2f acc1[8];
    #pragma unroll
    for (int j = 0; j < 8; ++j) acc1[j] = B1v(j);
    #pragma unroll
    for (int k = 0; k < 4; ++k) {
        v2f zk = s2(zv[k]);
        #pragma unroll
        for (int j = 0; j < 8; ++j) acc1[j] = pkfma(T1v(k, j), zk, acc1[j]);
    }
    float h1[16];
    #pragma unroll
    for (int j = 0; j < 8; ++j) {
        v2f r = __builtin_elementwise_max(acc1[j], vzero);
        h1[2*j] = r.x; h1[2*j+1] = r.y;
    }

    v2f acc2[16];
    #pragma unroll
    for (int j = 0; j < 16; ++j) acc2[j] = B2v(j);
    #pragma unroll
    for (int k = 0; k < 16; ++k) {
        v2f hk = s2(h1[k]);
        #pragma unroll
        for (int j = 0; j < 16; ++j) acc2[j] = pkfma(T2v(k, j), hk, acc2[j]);
    }
    float h2[32];
    #pragma unroll
    for (int j = 0; j < 16; ++j) {
        v2f r = __builtin_elementwise_max(acc2[j], vzero);
        h2[2*j] = r.x; h2[2*j+1] = r.y;
    }

    v2f acc3[8];
    #pragma unroll
    for (int j = 0; j < 8; ++j) acc3[j] = B3v(j);
    #pragma unroll
    for (int k = 0; k < 32; ++k) {
        v2f hk = s2(h2[k]);
        #pragma unroll
        for (int j = 0; j < 8; ++j) acc3[j] = pkfma(T3v(k, j), hk, acc3[j]);
    }

    // ---- store 16 f32 as 4x dwordx4 ----
    float4* op = reinterpret_cast<float4*>(outv) + (size_t)b * 4;
    op[0] = make_float4(acc3[0].x, acc3[0].y, acc3[1].x, acc3[1].y);
    op[1] = make_float4(acc3[2].x, acc3[2].y, acc3[3].x, acc3[3].y);
    op[2] = make_float4(acc3[4].x, acc3[4].y, acc3[5].x, acc3[5].y);
    op[3] = make_float4(acc3[6].x, acc3[6].y, acc3[7].x, acc3[7].y);
}

extern "C" void kernel_launch(void* const* d_in, const int* in_sizes, int n_in,
                              void* d_out, int out_size, void* d_ws, size_t ws_size,
                              hipStream_t stream) {
    const float* x  = (const float*)d_in[0];
    const float* qw = (const float*)d_in[1];
    const float* W1 = (const float*)d_in[2];
    const float* b1 = (const float*)d_in[3];
    const float* W2 = (const float*)d_in[4];
    const float* b2 = (const float*)d_in[5];
    const float* W3 = (const float*)d_in[6];
    const float* b3 = (const float*)d_in[7];
    float* out = (float*)d_out;

    int n = in_sizes[0] / 16;           // B
    int blocks = (n + 255) / 256;

    if (ws_size >= WS_FLOATS * sizeof(float)) {
        float* wf = (float*)d_ws;
        cvt_weights_kernel<<<5, 256, 0, stream>>>(qw, W1, b1, W2, b2, W3, b3, wf);
        qae_main<true><<<blocks, 256, 0, stream>>>(x, wf, qw, W1, b1, W2, b2, W3, b3,
                                                   out, n);
    } else {
        qae_main<false><<<blocks, 256, 0, stream>>>(x, nullptr, qw, W1, b1, W2, b2, W3, b3,
                                                    out, n);
    }
}

// Round 5
// 148.966 us; speedup vs baseline: 1.1284x; 1.0025x over previous
//
#include <hip/hip_runtime.h>

using u16 = unsigned short;
using u32 = unsigned int;
typedef float v2f   __attribute__((ext_vector_type(2)));
typedef float f32x4 __attribute__((ext_vector_type(4)));
typedef short s16x8 __attribute__((ext_vector_type(8)));

__device__ __forceinline__ float bf2f(u32 b) { return __uint_as_float(b << 16); }
__device__ __forceinline__ u32   f2bf(float f) {
    u32 u = __float_as_uint(f);
    return (u + 0x7FFFu + ((u >> 16) & 1u)) >> 16;   // RNE f32->bf16
}
__device__ __forceinline__ v2f pkfma(v2f a, v2f b, v2f c) { return __builtin_elementwise_fma(a, b, c); }
__device__ __forceinline__ v2f s2v(float x) { return (v2f){x, x}; }

// ---------------- single fused kernel ----------------
// Per-thread 4-qubit statevector in registers -> z[4]; decoder MLP via MFMA
// (each wave owns 64 batch rows). Weight B-fragments (hi/lo bf16 split) are
// built per block in LDS, then the same LDS is reused (union) as the
// inter-layer transpose buffer. No workspace, no second kernel -> single
// deterministic graph node (fixes round-4's graph-tripwire failure).
__global__ void __launch_bounds__(256) qae_fused(
    const float* __restrict__ x,  const float* __restrict__ qw,
    const float* __restrict__ W1, const float* __restrict__ b1,
    const float* __restrict__ W2, const float* __restrict__ b2,
    const float* __restrict__ W3, const float* __restrict__ b3,
    float* __restrict__ out, int n)
{
    int tid  = threadIdx.x;
    int b    = blockIdx.x * 256 + tid;
    int bc   = b < n ? b : n - 1;
    int lane = tid & 63;
    int quad = lane >> 4, col = lane & 15;
    int wbase = (tid >> 6) * 64;            // this wave's row base within block

    // frag: 8 fragments x 512 u16, fragment-ordered [lane*8+j]  (8 KB)
    //   pairs (hi,lo): 0,1=L1 | 2,3=L2 nt0 | 4,5=L2 nt1 | 6,7=L3
    //   element (lane,j): n = lane&15 (+16 for L2 nt1), k = (lane>>4)*8+j,
    //   zero for k >= K_layer (A-side garbage never multiplies nonzero B)
    // m: transpose buffers, reused after frag -> registers  (32 KB total)
    __shared__ union {
        u16 frag[8 * 512];
        struct { u16 Zb[256 * 4]; u16 H1[256 * 24]; u16 H2[256 * 36]; } m;
    } sh;

    // ---- issue x load first (HBM latency) ----
    const float4* xf = reinterpret_cast<const float4*>(x);
    float4 xa = xf[(size_t)bc * 4];
    float4 xc = xf[(size_t)bc * 4 + 1];

    // ---- build weight fragments in LDS: 16 elements per thread ----
    #pragma unroll
    for (int e = 0; e < 16; ++e) {
        int t  = tid * 16 + e;
        int f  = t >> 9, idx = t & 511;
        int ln = idx >> 3, j = idx & 7;
        int nn = ln & 15, qd = ln >> 4, k = qd * 8 + j;
        int ff = f >> 1;                    // 0:L1  1:L2t0  2:L2t1  3:L3
        float w = 0.f; bool valid = false;
        if      (ff == 0) { valid = (k < 4);  if (valid) w = W1[nn * 4 + k]; }
        else if (ff == 1) { valid = (k < 16); if (valid) w = W2[nn * 16 + k]; }
        else if (ff == 2) { valid = (k < 16); if (valid) w = W2[(16 + nn) * 16 + k]; }
        else              { valid = true;               w = W3[nn * 32 + k]; }
        u16 hb = (u16)f2bf(w);                       // hi = bf16(w)
        u16 lb = (u16)f2bf(w - bf2f(hb));            // lo = bf16(w - hi)
        sh.frag[t] = valid ? ((f & 1) ? lb : hb) : (u16)0;
    }

    // ---- trainable-RY constants (per-thread; 8 transcendentals) ----
    const float INV4PI = 0.07957747154594767f;       // half-angle -> revolutions
    float qc[4], qs[4];
    #pragma unroll
    for (int w = 0; w < 4; ++w) {
        float a = qw[2 * w];
        qc[w] = __builtin_amdgcn_cosf(a * INV4PI);
        qs[w] = __builtin_amdgcn_sinf(a * INV4PI);
    }

    // ================= quantum circuit (round-3 verified) =================
    float th[4] = { xa.x, xa.y, xa.z, xa.w };
    float ph[4] = { xc.x, xc.y, xc.z, xc.w };
    float u0r[4], u0i[4], u1r[4], u1i[4];
    #pragma unroll
    for (int i = 0; i < 4; ++i) {
        float ct = __builtin_amdgcn_cosf(th[i] * 0.25f);
        float st = __builtin_amdgcn_sinf(th[i] * 0.25f);
        float cp = __builtin_amdgcn_cosf(ph[i] * 0.25f);
        float sp = __builtin_amdgcn_sinf(ph[i] * 0.25f);
        u0r[i] = ct * cp;  u0i[i] = -ct * sp;
        u1r[i] = st * cp;  u1i[i] = st * sp;
    }
    float p01r[4], p01i[4], p23r[4], p23i[4];
    #pragma unroll
    for (int a = 0; a < 2; ++a)
        #pragma unroll
        for (int c = 0; c < 2; ++c) {
            float arq = a ? u1r[0] : u0r[0], aiq = a ? u1i[0] : u0i[0];
            float brq = c ? u1r[1] : u0r[1], biq = c ? u1i[1] : u0i[1];
            p01r[a*2+c] = arq*brq - aiq*biq;
            p01i[a*2+c] = arq*biq + aiq*brq;
            float crq = a ? u1r[2] : u0r[2], ciq = a ? u1i[2] : u0i[2];
            float drq = c ? u1r[3] : u0r[3], diq = c ? u1i[3] : u0i[3];
            p23r[a*2+c] = crq*drq - ciq*diq;
            p23i[a*2+c] = crq*diq + ciq*drq;
        }
    v2f amp[16];   // first CNOT chain folded as rename g(q)=(q0,q1^q0,q2^q1,q3^q2)
    #pragma unroll
    for (int i = 0; i < 16; ++i) {
        int q0=(i>>3)&1, q1=(i>>2)&1, q2=(i>>1)&1, q3=i&1;
        int g = (q0<<3) | ((q1^q0)<<2) | ((q2^q1)<<1) | (q3^q2);
        int hi = g >> 2, lo = g & 3;
        amp[i] = (v2f){ p01r[hi]*p23r[lo] - p01i[hi]*p23i[lo],
                        p01r[hi]*p23i[lo] + p01i[hi]*p23r[lo] };
    }
    #pragma unroll
    for (int w = 0; w < 4; ++w) {           // trainable RY (RZ dropped: phase-invisible)
        v2f vc = s2v(qc[w]), vs = s2v(qs[w]);
        int stride = 1 << (3 - w);
        #pragma unroll
        for (int m = 0; m < 16; ++m) {
            if (m & stride) continue;
            int i0 = m, i1 = m | stride;
            v2f a0 = amp[i0], a1 = amp[i1];
            amp[i0] = pkfma(vc, a0, -(vs * a1));
            amp[i1] = pkfma(vc, a1,  (vs * a0));
        }
    }
    float p[16];
    #pragma unroll
    for (int i = 0; i < 16; ++i) {          // second CNOT chain + |amp|^2
        int q0=(i>>3)&1, q1=(i>>2)&1, q2=(i>>1)&1, q3=i&1;
        int g = (q0<<3) | ((q1^q0)<<2) | ((q2^q1)<<1) | (q3^q2);
        v2f q = amp[g] * amp[g];
        p[i] = q.x + q.y;
    }
    float s2a[8], s4[4];
    #pragma unroll
    for (int j = 0; j < 8; ++j) s2a[j] = p[2*j] + p[2*j+1];
    #pragma unroll
    for (int j = 0; j < 4; ++j) s4[j] = s2a[2*j] + s2a[2*j+1];
    float zv[4];
    zv[0] = (s4[0] + s4[1]) - (s4[2] + s4[3]);
    zv[1] = (s4[0] - s4[1]) + (s4[2] - s4[3]);
    zv[2] = (s2a[0]-s2a[1]) + (s2a[2]-s2a[3]) + (s2a[4]-s2a[5]) + (s2a[6]-s2a[7]);
    zv[3] = (p[0]-p[1]) + (p[2]-p[3]) + (p[4]-p[5]) + (p[6]-p[7])
          + (p[8]-p[9]) + (p[10]-p[11]) + (p[12]-p[13]) + (p[14]-p[15]);

    // ---- frag LDS -> B-fragment registers (deferred: no overlap with amp regs) ----
    __syncthreads();                        // all frag writes visible
    union U { uint4 u; s16x8 s; };
    s16x8 Bf[8];
    #pragma unroll
    for (int f = 0; f < 8; ++f) {
        U cv; cv.u = *reinterpret_cast<const uint4*>(&sh.frag[f * 512 + lane * 8]);
        Bf[f] = cv.s;
    }
    float b1v = b1[col], b2v0 = b2[col], b2v1 = b2[16 + col], b3v = b3[col];
    __syncthreads();                        // all frag reads done before Zb overwrite

    // ================= MFMA MLP =================
    u32 zlo = f2bf(zv[0]) | (f2bf(zv[1]) << 16);
    u32 zhi = f2bf(zv[2]) | (f2bf(zv[3]) << 16);
    *reinterpret_cast<uint2*>(&sh.m.Zb[tid * 4]) = make_uint2(zlo, zhi);
    __syncthreads();

    // layer 1: 256x4 @ 4x16 (K=4 padded to 32; A/B zero beyond K)
    #pragma unroll
    for (int t = 0; t < 4; ++t) {
        int arow = wbase + t * 16 + col;                 // A: m = lane&15
        U av; av.u = make_uint4(0, 0, 0, 0);
        if (quad == 0) {                                 // k = quad*8+j -> only quad 0
            uint2 z = *reinterpret_cast<const uint2*>(&sh.m.Zb[arow * 4]);
            av.u.x = z.x; av.u.y = z.y;
        }
        f32x4 c = { b1v, b1v, b1v, b1v };                // bias by col (output feature)
        c = __builtin_amdgcn_mfma_f32_16x16x32_bf16(av.s, Bf[1], c, 0, 0, 0);  // lo
        c = __builtin_amdgcn_mfma_f32_16x16x32_bf16(av.s, Bf[0], c, 0, 0, 0);  // hi
        #pragma unroll
        for (int r = 0; r < 4; ++r) {                    // C/D: row=quad*4+r, col=lane&15
            int row = wbase + t * 16 + quad * 4 + r;
            sh.m.H1[row * 24 + col] = (u16)f2bf(fmaxf(c[r], 0.f));
        }
    }
    __syncthreads();

    // layer 2: 256x16 @ 16x32 (K=16 padded; quads 2,3 zero both sides)
    #pragma unroll
    for (int t = 0; t < 4; ++t) {
        int arow = wbase + t * 16 + col;
        U av; av.u = make_uint4(0, 0, 0, 0);
        if (quad < 2)
            av.u = *reinterpret_cast<const uint4*>(&sh.m.H1[arow * 24 + quad * 8]);
        #pragma unroll
        for (int nt = 0; nt < 2; ++nt) {
            float bv = nt ? b2v1 : b2v0;
            f32x4 c = { bv, bv, bv, bv };
            c = __builtin_amdgcn_mfma_f32_16x16x32_bf16(av.s, Bf[3 + 2*nt], c, 0, 0, 0);
            c = __builtin_amdgcn_mfma_f32_16x16x32_bf16(av.s, Bf[2 + 2*nt], c, 0, 0, 0);
            #pragma unroll
            for (int r = 0; r < 4; ++r) {
                int row = wbase + t * 16 + quad * 4 + r;
                sh.m.H2[row * 36 + nt * 16 + col] = (u16)f2bf(fmaxf(c[r], 0.f));
            }
        }
    }
    __syncthreads();

    // layer 3: 256x32 @ 32x16 (K=32 exact) -> global store
    #pragma unroll
    for (int t = 0; t < 4; ++t) {
        int arow = wbase + t * 16 + col;
        uint2 u0 = *reinterpret_cast<const uint2*>(&sh.m.H2[arow * 36 + quad * 8]);
        uint2 u1 = *reinterpret_cast<const uint2*>(&sh.m.H2[arow * 36 + quad * 8 + 4]);
        U av; av.u = make_uint4(u0.x, u0.y, u1.x, u1.y);
        f32x4 c = { b3v, b3v, b3v, b3v };
        c = __builtin_amdgcn_mfma_f32_16x16x32_bf16(av.s, Bf[7], c, 0, 0, 0);
        c = __builtin_amdgcn_mfma_f32_16x16x32_bf16(av.s, Bf[6], c, 0, 0, 0);
        int rowbase = blockIdx.x * 256 + wbase + t * 16 + quad * 4;
        #pragma unroll
        for (int r = 0; r < 4; ++r) {
            int grow = rowbase + r;
            if (grow < n) out[(size_t)grow * 16 + col] = c[r];  // 16 lanes = 64B segment
        }
    }
}

extern "C" void kernel_launch(void* const* d_in, const int* in_sizes, int n_in,
                              void* d_out, int out_size, void* d_ws, size_t ws_size,
                              hipStream_t stream) {
    const float* x  = (const float*)d_in[0];
    const float* qw = (const float*)d_in[1];
    const float* W1 = (const float*)d_in[2];
    const float* b1 = (const float*)d_in[3];
    const float* W2 = (const float*)d_in[4];
    const float* b2 = (const float*)d_in[5];
    const float* W3 = (const float*)d_in[6];
    const float* b3 = (const float*)d_in[7];
    float* out = (float*)d_out;

    int n = in_sizes[0] / 16;             // B
    int blocks = (n + 255) / 256;
    qae_fused<<<blocks, 256, 0, stream>>>(x, qw, W1, b1, W2, b2, W3, b3, out, n);
}

// Round 6
// 134.960 us; speedup vs baseline: 1.2455x; 1.1038x over previous
//
#include <hip/hip_runtime.h>

using u16 = unsigned short;
using u32 = unsigned int;
typedef float v2f   __attribute__((ext_vector_type(2)));
typedef float f32x4 __attribute__((ext_vector_type(4)));
typedef short s16x8 __attribute__((ext_vector_type(8)));

union FragU { u32 d[4]; s16x8 s; };

__device__ __forceinline__ u32 rne16(u32 u) { return (u + 0x7FFFu + ((u >> 16) & 1u)) >> 16; }
__device__ __forceinline__ u32 pk_bf16(float a, float b) {   // {lo=a, hi=b} RNE
    return rne16(__float_as_uint(a)) | (rne16(__float_as_uint(b)) << 16);
}
// weight split: hi = truncated bf16 pair, lo = RNE bf16 of exact residual
__device__ __forceinline__ void split2(float w0, float w1, u32& hi, u32& lo) {
    u32 u0 = __float_as_uint(w0), u1 = __float_as_uint(w1);
    hi = (u0 >> 16) | (u1 & 0xFFFF0000u);
    float r0 = w0 - __uint_as_float(u0 & 0xFFFF0000u);
    float r1 = w1 - __uint_as_float(u1 & 0xFFFF0000u);
    lo = pk_bf16(r0, r1);
}
__device__ __forceinline__ u32 bp(int ib, u32 v) {           // full-exec crossbar pull
    return (u32)__builtin_amdgcn_ds_bpermute(ib, (int)v);
}
__device__ __forceinline__ v2f pkfma(v2f a, v2f b, v2f c) { return __builtin_elementwise_fma(a, b, c); }
__device__ __forceinline__ v2f s2v(float x) { return (v2f){x, x}; }
__device__ __forceinline__ f32x4 tov(float4 v) { return (f32x4){v.x, v.y, v.z, v.w}; }
#define MFMA16 __builtin_amdgcn_mfma_f32_16x16x32_bf16

// One kernel, no LDS, no barriers. Thread = 1 batch row (quantum part);
// wave = 64 rows = 4 MFMA tiles (MLP as C = W·H^T, weights in A, activations
// in B, inter-layer transpose via ds_bpermute).
__global__ void __launch_bounds__(256) qae_bperm(
    const float* __restrict__ x,  const float* __restrict__ qw,
    const float* __restrict__ W1, const float* __restrict__ b1,
    const float* __restrict__ W2, const float* __restrict__ b2,
    const float* __restrict__ W3, const float* __restrict__ b3,
    float* __restrict__ out, int n)
{
    int tid  = threadIdx.x;
    int b    = blockIdx.x * 256 + tid;
    int bc   = b < n ? b : n - 1;
    int lane = tid & 63;
    int vn   = lane & 15, vq = lane >> 4;
    int gbase = blockIdx.x * 256 + (tid - lane);     // wave's first global row

    // ---- x load first (HBM latency) ----
    const float4* xf = reinterpret_cast<const float4*>(x);
    float4 xa = xf[(size_t)bc * 4];
    float4 xc = xf[(size_t)bc * 4 + 1];

    // ================= quantum circuit (verified r3/r5) =================
    float th[4] = { xa.x, xa.y, xa.z, xa.w };
    float ph[4] = { xc.x, xc.y, xc.z, xc.w };
    float u0r[4], u0i[4], u1r[4], u1i[4];
    #pragma unroll
    for (int i = 0; i < 4; ++i) {
        float ct = __builtin_amdgcn_cosf(th[i] * 0.25f);
        float st = __builtin_amdgcn_sinf(th[i] * 0.25f);
        float cp = __builtin_amdgcn_cosf(ph[i] * 0.25f);
        float sp = __builtin_amdgcn_sinf(ph[i] * 0.25f);
        u0r[i] = ct * cp;  u0i[i] = -ct * sp;
        u1r[i] = st * cp;  u1i[i] = st * sp;
    }
    float p01r[4], p01i[4], p23r[4], p23i[4];
    #pragma unroll
    for (int a = 0; a < 2; ++a)
        #pragma unroll
        for (int c = 0; c < 2; ++c) {
            float arq = a ? u1r[0] : u0r[0], aiq = a ? u1i[0] : u0i[0];
            float brq = c ? u1r[1] : u0r[1], biq = c ? u1i[1] : u0i[1];
            p01r[a*2+c] = arq*brq - aiq*biq;
            p01i[a*2+c] = arq*biq + aiq*brq;
            float crq = a ? u1r[2] : u0r[2], ciq = a ? u1i[2] : u0i[2];
            float drq = c ? u1r[3] : u0r[3], diq = c ? u1i[3] : u0i[3];
            p23r[a*2+c] = crq*drq - ciq*diq;
            p23i[a*2+c] = crq*diq + ciq*drq;
        }
    v2f amp[16];   // first CNOT chain folded: g(q)=(q0,q1^q0,q2^q1,q3^q2)
    #pragma unroll
    for (int i = 0; i < 16; ++i) {
        int q0i=(i>>3)&1, q1i=(i>>2)&1, q2i=(i>>1)&1, q3i=i&1;
        int g = (q0i<<3) | ((q1i^q0i)<<2) | ((q2i^q1i)<<1) | (q3i^q2i);
        int hi = g >> 2, lo = g & 3;
        amp[i] = (v2f){ p01r[hi]*p23r[lo] - p01i[hi]*p23i[lo],
                        p01r[hi]*p23i[lo] + p01i[hi]*p23r[lo] };
    }
    const float INV4PI = 0.07957747154594767f;
    #pragma unroll
    for (int w = 0; w < 4; ++w) {           // trainable RY (RZ phase-invisible)
        float a = qw[2 * w];                 // uniform -> s_load
        v2f vc = s2v(__builtin_amdgcn_cosf(a * INV4PI));
        v2f vs = s2v(__builtin_amdgcn_sinf(a * INV4PI));
        int stride = 1 << (3 - w);
        #pragma unroll
        for (int m = 0; m < 16; ++m) {
            if (m & stride) continue;
            int i0 = m, i1 = m | stride;
            v2f a0 = amp[i0], a1 = amp[i1];
            amp[i0] = pkfma(vc, a0, -(vs * a1));
            amp[i1] = pkfma(vc, a1,  (vs * a0));
        }
    }
    float p[16];
    #pragma unroll
    for (int i = 0; i < 16; ++i) {          // second CNOT chain + |amp|^2
        int q0i=(i>>3)&1, q1i=(i>>2)&1, q2i=(i>>1)&1, q3i=i&1;
        int g = (q0i<<3) | ((q1i^q0i)<<2) | ((q2i^q1i)<<1) | (q3i^q2i);
        v2f q = amp[g] * amp[g];
        p[i] = q.x + q.y;
    }
    float s2a[8], s4[4];
    #pragma unroll
    for (int j = 0; j < 8; ++j) s2a[j] = p[2*j] + p[2*j+1];
    #pragma unroll
    for (int j = 0; j < 4; ++j) s4[j] = s2a[2*j] + s2a[2*j+1];
    float zv0 = (s4[0] + s4[1]) - (s4[2] + s4[3]);
    float zv1 = (s4[0] - s4[1]) + (s4[2] - s4[3]);
    float zv2 = (s2a[0]-s2a[1]) + (s2a[2]-s2a[3]) + (s2a[4]-s2a[5]) + (s2a[6]-s2a[7]);
    float zv3 = (p[0]-p[1]) + (p[2]-p[3]) + (p[4]-p[5]) + (p[6]-p[7])
              + (p[8]-p[9]) + (p[10]-p[11]) + (p[12]-p[13]) + (p[14]-p[15]);

    // z packed bf16 pairs (k-order: low=even k)
    u32 zd0 = pk_bf16(zv0, zv1);
    u32 zd1 = pk_bf16(zv2, zv3);

    // ================= weight A-fragments (per-lane, from L1/L2 cache) =====
    // A[m][k]: m = lane&15, k = (lane>>4)*8 + j.  Zero where k >= K_layer
    // (B-side garbage at those k multiplies 0 -> safe; sources always finite).
    bool q0 = (vq == 0), qlt2 = (vq < 2);
    FragU A1h, A1l;
    {
        float4 w = reinterpret_cast<const float4*>(W1)[vn];   // W1 row vn, K=4
        u32 h0,l0,h1,l1; split2(w.x, w.y, h0, l0); split2(w.z, w.w, h1, l1);
        A1h.d[0] = q0 ? h0 : 0; A1h.d[1] = q0 ? h1 : 0; A1h.d[2] = 0; A1h.d[3] = 0;
        A1l.d[0] = q0 ? l0 : 0; A1l.d[1] = q0 ? l1 : 0; A1l.d[2] = 0; A1l.d[3] = 0;
    }
    FragU A2ah, A2al, A2bh, A2bl, A3h, A3l;
    {   // W2 tiles (K=16, valid q<2; q>=2 reads aliased-but-in-bounds then zeroed)
        const float4* p0 = reinterpret_cast<const float4*>(W2 + vn * 16 + (vq & 1) * 8);
        const float4* p1 = reinterpret_cast<const float4*>(W2 + (16 + vn) * 16 + (vq & 1) * 8);
        float4 a0 = p0[0], a1 = p0[1], c0 = p1[0], c1 = p1[1];
        u32 h, l;
        split2(a0.x,a0.y,h,l); A2ah.d[0]=qlt2?h:0; A2al.d[0]=qlt2?l:0;
        split2(a0.z,a0.w,h,l); A2ah.d[1]=qlt2?h:0; A2al.d[1]=qlt2?l:0;
        split2(a1.x,a1.y,h,l); A2ah.d[2]=qlt2?h:0; A2al.d[2]=qlt2?l:0;
        split2(a1.z,a1.w,h,l); A2ah.d[3]=qlt2?h:0; A2al.d[3]=qlt2?l:0;
        split2(c0.x,c0.y,h,l); A2bh.d[0]=qlt2?h:0; A2bl.d[0]=qlt2?l:0;
        split2(c0.z,c0.w,h,l); A2bh.d[1]=qlt2?h:0; A2bl.d[1]=qlt2?l:0;
        split2(c1.x,c1.y,h,l); A2bh.d[2]=qlt2?h:0; A2bl.d[2]=qlt2?l:0;
        split2(c1.z,c1.w,h,l); A2bh.d[3]=qlt2?h:0; A2bl.d[3]=qlt2?l:0;
        // W3 (K=32 exact, all lanes valid)
        const float4* p3 = reinterpret_cast<const float4*>(W3 + vn * 32 + vq * 8);
        float4 e0 = p3[0], e1 = p3[1];
        split2(e0.x,e0.y,h,l); A3h.d[0]=h; A3l.d[0]=l;
        split2(e0.z,e0.w,h,l); A3h.d[1]=h; A3l.d[1]=l;
        split2(e1.x,e1.y,h,l); A3h.d[2]=h; A3l.d[2]=l;
        split2(e1.z,e1.w,h,l); A3h.d[3]=h; A3l.d[3]=l;
    }
    // biases along C rows (features = quad*4+r)
    float4 c1b = reinterpret_cast<const float4*>(b1)[vq];
    float4 c2b0 = reinterpret_cast<const float4*>(b2)[vq];
    float4 c2b1 = reinterpret_cast<const float4*>(b2)[4 + vq];
    float4 c3b = reinterpret_cast<const float4*>(b3)[vq];

    // bpermute byte-indices for C->B transposes (mod-4 quad keeps idx in-wave;
    // out-of-K regions land on A=0 so gathered garbage is harmless)
    int i2a = ((((2 * vq)    ) & 3) * 16 + vn) * 4;
    int i2b = ((((2 * vq) + 1) & 3) * 16 + vn) * 4;

    // ================= MLP: 4 tiles of 16 rows per wave =================
    #pragma unroll
    for (int t = 0; t < 4; ++t) {
        // L1: B = z^T gather (k<4 live; rest covered by A1 zeros)
        int viL = (t * 16 + vn) * 4;
        FragU B1; B1.d[0] = bp(viL, zd0); B1.d[1] = bp(viL, zd1); B1.d[2] = 0; B1.d[3] = 0;
        f32x4 c1 = tov(c1b);
        c1 = MFMA16(A1l.s, B1.s, c1, 0, 0, 0);
        c1 = MFMA16(A1h.s, B1.s, c1, 0, 0, 0);
        u32 da0 = pk_bf16(fmaxf(c1[0], 0.f), fmaxf(c1[1], 0.f));   // features q*4+0,1
        u32 da1 = pk_bf16(fmaxf(c1[2], 0.f), fmaxf(c1[3], 0.f));   // features q*4+2,3

        // L2: B[k=h1 feature][n] via 4 bpermutes
        FragU B2;
        B2.d[0] = bp(i2a, da0); B2.d[1] = bp(i2a, da1);
        B2.d[2] = bp(i2b, da0); B2.d[3] = bp(i2b, da1);
        f32x4 ca = tov(c2b0), cb = tov(c2b1);
        ca = MFMA16(A2al.s, B2.s, ca, 0, 0, 0);
        ca = MFMA16(A2ah.s, B2.s, ca, 0, 0, 0);
        cb = MFMA16(A2bl.s, B2.s, cb, 0, 0, 0);
        cb = MFMA16(A2bh.s, B2.s, cb, 0, 0, 0);
        u32 ea0 = pk_bf16(fmaxf(ca[0],0.f), fmaxf(ca[1],0.f));   // features  q*4+0,1
        u32 ea1 = pk_bf16(fmaxf(ca[2],0.f), fmaxf(ca[3],0.f));
        u32 eb0 = pk_bf16(fmaxf(cb[0],0.f), fmaxf(cb[1],0.f));   // features 16+q*4+..
        u32 eb1 = pk_bf16(fmaxf(cb[2],0.f), fmaxf(cb[3],0.f));

        // L3: B over 32 features; tile-select (q<2 -> features<16) after
        // full-exec bpermutes (no divergent cross-lane ops)
        u32 s0a = bp(i2a, ea0), s0b = bp(i2a, eb0);
        u32 s1a = bp(i2a, ea1), s1b = bp(i2a, eb1);
        u32 s2_ = bp(i2b, ea0), s2b = bp(i2b, eb0);
        u32 s3a = bp(i2b, ea1), s3b = bp(i2b, eb1);
        FragU B3;
        B3.d[0] = qlt2 ? s0a : s0b;
        B3.d[1] = qlt2 ? s1a : s1b;
        B3.d[2] = qlt2 ? s2_ : s2b;
        B3.d[3] = qlt2 ? s3a : s3b;
        f32x4 c3 = tov(c3b);
        c3 = MFMA16(A3l.s, B3.s, c3, 0, 0, 0);
        c3 = MFMA16(A3h.s, B3.s, c3, 0, 0, 0);

        // store: row = batch (col n), features q*4..q*4+3 -> contiguous 16B
        int R = gbase + t * 16 + vn;
        if (R < n)
            *reinterpret_cast<float4*>(out + (size_t)R * 16 + vq * 4) =
                make_float4(c3[0], c3[1], c3[2], c3[3]);
    }
}

extern "C" void kernel_launch(void* const* d_in, const int* in_sizes, int n_in,
                              void* d_out, int out_size, void* d_ws, size_t ws_size,
                              hipStream_t stream) {
    const float* x  = (const float*)d_in[0];
    const float* qw = (const float*)d_in[1];
    const float* W1 = (const float*)d_in[2];
    const float* b1 = (const float*)d_in[3];
    const float* W2 = (const float*)d_in[4];
    const float* b2 = (const float*)d_in[5];
    const float* W3 = (const float*)d_in[6];
    const float* b3 = (const float*)d_in[7];
    float* out = (float*)d_out;

    int n = in_sizes[0] / 16;             // B
    int blocks = (n + 255) / 256;
    qae_bperm<<<blocks, 256, 0, stream>>>(x, qw, W1, b1, W2, b2, W3, b3, out, n);
}